// Round 1
// baseline (451.927 us; speedup 1.0000x reference)
//
#include <hip/hip_runtime.h>
#include <cstdint>

// ---------------------------------------------------------------------------
// PaddedSoftmaxSHCSA: y = softmax(mask(scale * (xW+b)_q @ (xW+b)_k^T)) @ (xW+b)_v
// T=4096, C=2048, NF=2048, 3*NF=6144. fp32 in/out, bf16 MFMA compute.
//
// Pipeline (all on `stream`):
//   1. cast_x:        x fp32 (4096x2048) -> xb bf16
//   2. transpose_W:   W fp32 (2048x6144) -> Wt bf16 (6144x2048)  [B^T layout]
//   3. qkv_gemm:      qkv = xb @ Wt^T + b; writes qb,kb (4096x2048 bf16),
//                     vT (2048x4096 bf16, transposed for PV B-operand)
//   4. sc_gemm:       S = scale * qb @ kb^T with causal+padding mask fused;
//                     fully-masked 128x128 blocks skip the K-loop
//   5. softmax_rows:  P = row-softmax(S) bf16 (P reuses dead qb/kb region)
//   6. pv_gemm:       y = P @ vT^T, K-loop truncated at the causal boundary
//
// GEMM core: m97 structure — 128x128 tile, BK=32, 4 waves/block, 4x4
// mfma_f32_16x16x32_bf16 per wave, global_load_lds width=16 staging.
// ---------------------------------------------------------------------------

#define T_DIM 4096
#define C_DIM 2048
#define NF    2048
#define N3    6144
#define NEGV  (-1e30f)

typedef __bf16 bf16x8 __attribute__((ext_vector_type(8)));
typedef __bf16 bf16x4 __attribute__((ext_vector_type(4)));
typedef float  f32x4  __attribute__((ext_vector_type(4)));

__device__ __forceinline__ void async_cp16(const void* g, void* l) {
    __builtin_amdgcn_global_load_lds(
        reinterpret_cast<const __attribute__((address_space(1))) unsigned int*>(
            reinterpret_cast<uintptr_t>(g)),
        reinterpret_cast<__attribute__((address_space(3))) unsigned int*>(
            reinterpret_cast<uintptr_t>(l)),
        16, 0, 0);
}

// Shared 128x128-tile GEMM K-loop: C[m0..+128, n0..+128] += A @ B^T
// A: (M x K) row-major, lda elems; B: (N x K) row-major, ldb elems.
__device__ __forceinline__ void gemm_loop(const __bf16* A, const __bf16* B,
                                          int lda, int ldb, int m0, int n0,
                                          int kiters, __bf16* As, __bf16* Bs,
                                          f32x4 (&acc)[4][4]) {
    const int t    = threadIdx.x;          // 0..255
    const int wv   = t >> 6;               // wave 0..3
    const int lane = t & 63;
    const int srow = t >> 2;               // staging row 0..63
    const int scol = (t & 3) << 3;         // staging col 0,8,16,24
    const int wm   = (wv >> 1) << 6;       // wave m offset 0/64
    const int wn   = (wv & 1) << 6;        // wave n offset 0/64
    const int lrow = lane & 15;
    const int kq   = (lane >> 4) << 3;     // 0,8,16,24

    const __bf16* ga = A + (size_t)(m0 + srow) * lda + scol;
    const __bf16* gb = B + (size_t)(n0 + srow) * ldb + scol;

    for (int kk = 0; kk < kiters; ++kk) {
        // stage A tile (128x32) and B tile (128x32); each issue = 4KB (64 rows)
        async_cp16(ga,                       &As[wv * 512]);
        async_cp16(ga + (size_t)64 * lda,    &As[wv * 512 + 2048]);
        async_cp16(gb,                       &Bs[wv * 512]);
        async_cp16(gb + (size_t)64 * ldb,    &Bs[wv * 512 + 2048]);
        ga += 32; gb += 32;
        __syncthreads();   // compiler emits vmcnt(0) drain before s_barrier

        bf16x8 af[4], bfr[4];
#pragma unroll
        for (int mi = 0; mi < 4; ++mi)
            af[mi] = *(const bf16x8*)&As[(wm + mi * 16 + lrow) * 32 + kq];
#pragma unroll
        for (int ni = 0; ni < 4; ++ni)
            bfr[ni] = *(const bf16x8*)&Bs[(wn + ni * 16 + lrow) * 32 + kq];
#pragma unroll
        for (int mi = 0; mi < 4; ++mi)
#pragma unroll
            for (int ni = 0; ni < 4; ++ni)
                acc[mi][ni] = __builtin_amdgcn_mfma_f32_16x16x32_bf16(
                    af[mi], bfr[ni], acc[mi][ni], 0, 0, 0);
        __syncthreads();   // protect LDS before next-iter staging overwrite
    }
}

// ---------------- 1. cast x -> bf16 ----------------
__global__ void cast_x_kernel(const float* __restrict__ x,
                              __bf16* __restrict__ xb, int n4) {
    int stride = gridDim.x * blockDim.x;
    for (int i = blockIdx.x * blockDim.x + threadIdx.x; i < n4; i += stride) {
        float4 v = ((const float4*)x)[i];
        bf16x4 o;
        o[0] = (__bf16)v.x; o[1] = (__bf16)v.y;
        o[2] = (__bf16)v.z; o[3] = (__bf16)v.w;
        ((bf16x4*)xb)[i] = o;
    }
}

// ---------------- 2. transpose-cast W (2048x6144) -> Wt (6144x2048) --------
__global__ void transpose_w_kernel(const float* __restrict__ W,
                                   __bf16* __restrict__ Wt) {
    __shared__ float tile[32][33];
    int bx = blockIdx.x * 32;  // W col / Wt row
    int by = blockIdx.y * 32;  // W row / Wt col
    int tx = threadIdx.x, ty = threadIdx.y;  // (32,8)
#pragma unroll
    for (int i = 0; i < 32; i += 8)
        tile[ty + i][tx] = W[(size_t)(by + ty + i) * N3 + bx + tx];
    __syncthreads();
#pragma unroll
    for (int i = 0; i < 32; i += 8)
        Wt[(size_t)(bx + ty + i) * C_DIM + by + tx] = (__bf16)tile[tx][ty + i];
}

// ---------------- 3. QKV GEMM ----------------
__global__ void __launch_bounds__(256)
qkv_gemm_kernel(const __bf16* __restrict__ xb, const __bf16* __restrict__ Wt,
                const float* __restrict__ bias, __bf16* __restrict__ qb,
                __bf16* __restrict__ kb, __bf16* __restrict__ vT) {
    __shared__ __bf16 As[128 * 32];
    __shared__ __bf16 Bs[128 * 32];
    f32x4 acc[4][4] = {};
    const int m0 = blockIdx.x * 128, n0 = blockIdx.y * 128;
    gemm_loop(xb, Wt, C_DIM, C_DIM, m0, n0, C_DIM / 32, As, Bs, acc);

    const int t = threadIdx.x, wv = t >> 6, lane = t & 63;
    const int wm = (wv >> 1) << 6, wn = (wv & 1) << 6;
    const int rq = (lane >> 4) << 2, cn = lane & 15;
#pragma unroll
    for (int mi = 0; mi < 4; ++mi)
#pragma unroll
        for (int ni = 0; ni < 4; ++ni) {
            int col = n0 + wn + ni * 16 + cn;
            float bv = bias[col];
#pragma unroll
            for (int r = 0; r < 4; ++r) {
                int row = m0 + wm + mi * 16 + rq + r;
                float val = acc[mi][ni][r] + bv;
                if (col < NF)
                    qb[(size_t)row * NF + col] = (__bf16)val;
                else if (col < 2 * NF)
                    kb[(size_t)row * NF + (col - NF)] = (__bf16)val;
                else
                    vT[(size_t)(col - 2 * NF) * T_DIM + row] = (__bf16)val;
            }
        }
}

// ---------------- 4. S = scale * q @ k^T with fused mask ----------------
__global__ void __launch_bounds__(256)
sc_gemm_kernel(const __bf16* __restrict__ qb, const __bf16* __restrict__ kb,
               float* __restrict__ S, const int* __restrict__ npadd_p) {
    __shared__ __bf16 As[128 * 32];
    __shared__ __bf16 Bs[128 * 32];
    const int m0 = blockIdx.x * 128, n0 = blockIdx.y * 128;
    const int npadd = *npadd_p;
    const int t = threadIdx.x;

    // fully-masked tile: above diagonal, or entirely in row/col padding
    if (n0 >= m0 + 128 || n0 + 128 <= npadd || m0 + 128 <= npadd) {
        float4 neg4 = make_float4(NEGV, NEGV, NEGV, NEGV);
        float4* S4 = (float4*)S;
        for (int i = t; i < 128 * 32; i += 256) {
            int row = i >> 5, c4 = i & 31;
            S4[(size_t)(m0 + row) * (T_DIM / 4) + (n0 >> 2) + c4] = neg4;
        }
        return;
    }

    f32x4 acc[4][4] = {};
    gemm_loop(qb, kb, NF, NF, m0, n0, NF / 32, As, Bs, acc);

    const float scale = 0.022097086912079608f;  // 1/sqrt(2048)
    const int wv = t >> 6, lane = t & 63;
    const int wm = (wv >> 1) << 6, wn = (wv & 1) << 6;
    const int rq = (lane >> 4) << 2, cn = lane & 15;
#pragma unroll
    for (int mi = 0; mi < 4; ++mi)
#pragma unroll
        for (int ni = 0; ni < 4; ++ni) {
            int j = n0 + wn + ni * 16 + cn;
#pragma unroll
            for (int r = 0; r < 4; ++r) {
                int i = m0 + wm + mi * 16 + rq + r;
                bool ok = (j <= i) && (j >= npadd) && (i >= npadd);
                S[(size_t)i * T_DIM + j] = ok ? acc[mi][ni][r] * scale : NEGV;
            }
        }
}

// ---------------- 5. row softmax, fp32 -> bf16 ----------------
__global__ void __launch_bounds__(256)
softmax_kernel(const float* __restrict__ S, __bf16* __restrict__ P,
               const int* __restrict__ npadd_p) {
    const int row = blockIdx.x;
    const int t = threadIdx.x, lane = t & 63, wv = t >> 6;
    const int npadd = *npadd_p;
    __bf16* prow = P + (size_t)row * T_DIM;

    if (row < npadd) {  // padding row: p == 0
        float4 z = make_float4(0.f, 0.f, 0.f, 0.f);
        float4* p4 = (float4*)prow;  // 4096 bf16 = 512 x 16B
        for (int i = t; i < 512; i += 256) p4[i] = z;
        return;
    }

    const float* srow = S + (size_t)row * T_DIM;
    float vals[16];
    float mx = -3.0e38f;
#pragma unroll
    for (int c = 0; c < 4; ++c) {
        float4 v = ((const float4*)srow)[c * 256 + t];
        vals[c * 4 + 0] = v.x; vals[c * 4 + 1] = v.y;
        vals[c * 4 + 2] = v.z; vals[c * 4 + 3] = v.w;
        mx = fmaxf(mx, fmaxf(fmaxf(v.x, v.y), fmaxf(v.z, v.w)));
    }
    __shared__ float wred[8];
#pragma unroll
    for (int o = 32; o > 0; o >>= 1) mx = fmaxf(mx, __shfl_xor(mx, o));
    if (lane == 0) wred[wv] = mx;
    __syncthreads();
    mx = fmaxf(fmaxf(wred[0], wred[1]), fmaxf(wred[2], wred[3]));

    float sm = 0.f;
#pragma unroll
    for (int k = 0; k < 16; ++k) {
        vals[k] = exp2f((vals[k] - mx) * 1.4426950408889634f);
        sm += vals[k];
    }
#pragma unroll
    for (int o = 32; o > 0; o >>= 1) sm += __shfl_xor(sm, o);
    if (lane == 0) wred[4 + wv] = sm;
    __syncthreads();
    sm = (wred[4] + wred[5]) + (wred[6] + wred[7]);
    float inv = 1.0f / sm;

#pragma unroll
    for (int c = 0; c < 4; ++c) {
        bf16x4 o;
        o[0] = (__bf16)(vals[c * 4 + 0] * inv);
        o[1] = (__bf16)(vals[c * 4 + 1] * inv);
        o[2] = (__bf16)(vals[c * 4 + 2] * inv);
        o[3] = (__bf16)(vals[c * 4 + 3] * inv);
        ((bf16x4*)prow)[c * 256 + t] = o;
    }
}

// ---------------- 6. y = P @ V ----------------
__global__ void __launch_bounds__(256)
pv_gemm_kernel(const __bf16* __restrict__ P, const __bf16* __restrict__ vT,
               float* __restrict__ out) {
    __shared__ __bf16 As[128 * 32];
    __shared__ __bf16 Bs[128 * 32];
    f32x4 acc[4][4] = {};
    const int m0 = blockIdx.x * 128, n0 = blockIdx.y * 128;
    const int kiters = (blockIdx.x + 1) * 4;  // causal: P[i][j]=0 for j>i
    gemm_loop(P, vT, T_DIM, T_DIM, m0, n0, kiters, As, Bs, acc);

    const int t = threadIdx.x, wv = t >> 6, lane = t & 63;
    const int wm = (wv >> 1) << 6, wn = (wv & 1) << 6;
    const int rq = (lane >> 4) << 2, cn = lane & 15;
#pragma unroll
    for (int mi = 0; mi < 4; ++mi)
#pragma unroll
        for (int ni = 0; ni < 4; ++ni) {
            int j = n0 + wn + ni * 16 + cn;
#pragma unroll
            for (int r = 0; r < 4; ++r) {
                int i = m0 + wm + mi * 16 + rq + r;
                out[(size_t)i * NF + j] = acc[mi][ni][r];
            }
        }
}

extern "C" void kernel_launch(void* const* d_in, const int* in_sizes, int n_in,
                              void* d_out, int out_size, void* d_ws,
                              size_t ws_size, hipStream_t stream) {
    const float* x = (const float*)d_in[0];
    const float* W = (const float*)d_in[1];
    const float* b = (const float*)d_in[2];
    const int* npadd = (const int*)d_in[3];
    float* out = (float*)d_out;

    char* ws = (char*)d_ws;
    // layout (152 MB total):
    __bf16* xb = (__bf16*)(ws);                          // 16 MB [0,16)
    __bf16* Wt = (__bf16*)(ws + (16ull << 20));          // 24 MB [16,40)
    __bf16* qb = (__bf16*)(ws + (40ull << 20));          // 16 MB [40,56)
    __bf16* kb = (__bf16*)(ws + (56ull << 20));          // 16 MB [56,72)
    __bf16* vT = (__bf16*)(ws + (72ull << 20));          // 16 MB [72,88)
    float*  S  = (float*)(ws + (88ull << 20));           // 64 MB [88,152)
    __bf16* P  = (__bf16*)(ws + (40ull << 20));          // 32 MB reuse qb+kb

    cast_x_kernel<<<2048, 256, 0, stream>>>(x, xb, (T_DIM * C_DIM) / 4);
    transpose_w_kernel<<<dim3(N3 / 32, C_DIM / 32), dim3(32, 8), 0, stream>>>(W, Wt);
    qkv_gemm_kernel<<<dim3(T_DIM / 128, N3 / 128), 256, 0, stream>>>(xb, Wt, b,
                                                                     qb, kb, vT);
    sc_gemm_kernel<<<dim3(T_DIM / 128, T_DIM / 128), 256, 0, stream>>>(qb, kb, S,
                                                                       npadd);
    softmax_kernel<<<T_DIM, 256, 0, stream>>>(S, P, npadd);
    pv_gemm_kernel<<<dim3(T_DIM / 128, NF / 128), 256, 0, stream>>>(P, vT, out);
}

// Round 2
// 450.567 us; speedup vs baseline: 1.0030x; 1.0030x over previous
//
#include <hip/hip_runtime.h>
#include <cstdint>

// ---------------------------------------------------------------------------
// PaddedSoftmaxSHCSA: y = softmax(mask(scale * (xW+b)_q @ (xW+b)_k^T)) @ (xW+b)_v
// T=4096, C=2048, NF=2048, 3*NF=6144. fp32 in/out, bf16 MFMA compute.
//
// Round 2 changes:
//  * XOR-swizzled LDS layout in the GEMM core: phys_chunk = log_chunk ^
//    ((row>>1)&3) (16B chunks). Kills the 8-way quarter-wave bank conflict
//    of the row*64B-stride ds_read_b128 pattern (SQ_LDS_BANK_CONFLICT was
//    1.26e7 = ~14% of QKV cycles). Staging side compensates by permuting the
//    per-lane GLOBAL source column (LDS dest of global_load_lds is fixed at
//    base + lane*16, but each lane supplies its own global address).
//  * sc_gemm no longer writes the masked region at all (fully-above-diagonal
//    blocks return immediately; no elementwise mask). Softmax applies the
//    causal/padding mask analytically and only reads 1024-col chunks with
//    base <= row. Saves ~60 MB of HBM traffic.
// ---------------------------------------------------------------------------

#define T_DIM 4096
#define C_DIM 2048
#define NF    2048
#define N3    6144
#define NEGV  (-1e30f)

typedef __bf16 bf16x8 __attribute__((ext_vector_type(8)));
typedef __bf16 bf16x4 __attribute__((ext_vector_type(4)));
typedef float  f32x4  __attribute__((ext_vector_type(4)));

__device__ __forceinline__ void async_cp16(const void* g, void* l) {
    __builtin_amdgcn_global_load_lds(
        reinterpret_cast<const __attribute__((address_space(1))) unsigned int*>(
            reinterpret_cast<uintptr_t>(g)),
        reinterpret_cast<__attribute__((address_space(3))) unsigned int*>(
            reinterpret_cast<uintptr_t>(l)),
        16, 0, 0);
}

// Shared 128x128-tile GEMM K-loop: C[m0..+128, n0..+128] += A @ B^T
// A: (M x K) row-major, lda elems; B: (N x K) row-major, ldb elems.
// LDS layout is XOR-swizzled: element (row, 8c+e) lives at
// row*32 + (c ^ ((row>>1)&3))*8 + e.
__device__ __forceinline__ void gemm_loop(const __bf16* A, const __bf16* B,
                                          int lda, int ldb, int m0, int n0,
                                          int kiters, __bf16* As, __bf16* Bs,
                                          f32x4 (&acc)[4][4]) {
    const int t    = threadIdx.x;          // 0..255
    const int wv   = t >> 6;               // wave 0..3
    const int lane = t & 63;
    const int srow = t >> 2;               // staging row 0..63
    // lane's LDS slot holds phys chunk (t&3) of row srow -> load the logical
    // chunk that maps there: c_log = c_phys ^ swz(row). (+64-row issue has the
    // same swz since 64 preserves (row>>1)&3.)
    const int scol = (((t & 3) ^ ((srow >> 1) & 3)) << 3);
    const int wm   = (wv >> 1) << 6;       // wave m offset 0/64
    const int wn   = (wv & 1) << 6;        // wave n offset 0/64
    const int lrow = lane & 15;
    const int kc   = lane >> 4;            // logical 16B chunk 0..3
    const int swz  = (lrow >> 1) & 3;      // row-dependent (mi*16 preserves it)
    const int rcol = ((kc ^ swz) << 3);    // physical column in LDS row

    const __bf16* ga = A + (size_t)(m0 + srow) * lda + scol;
    const __bf16* gb = B + (size_t)(n0 + srow) * ldb + scol;

    for (int kk = 0; kk < kiters; ++kk) {
        // stage A tile (128x32) and B tile (128x32); each issue = 4KB (64 rows)
        async_cp16(ga,                       &As[wv * 512]);
        async_cp16(ga + (size_t)64 * lda,    &As[wv * 512 + 2048]);
        async_cp16(gb,                       &Bs[wv * 512]);
        async_cp16(gb + (size_t)64 * ldb,    &Bs[wv * 512 + 2048]);
        ga += 32; gb += 32;
        __syncthreads();   // compiler emits vmcnt(0) drain before s_barrier

        bf16x8 af[4], bfr[4];
#pragma unroll
        for (int mi = 0; mi < 4; ++mi)
            af[mi] = *(const bf16x8*)&As[(wm + mi * 16 + lrow) * 32 + rcol];
#pragma unroll
        for (int ni = 0; ni < 4; ++ni)
            bfr[ni] = *(const bf16x8*)&Bs[(wn + ni * 16 + lrow) * 32 + rcol];
#pragma unroll
        for (int mi = 0; mi < 4; ++mi)
#pragma unroll
            for (int ni = 0; ni < 4; ++ni)
                acc[mi][ni] = __builtin_amdgcn_mfma_f32_16x16x32_bf16(
                    af[mi], bfr[ni], acc[mi][ni], 0, 0, 0);
        __syncthreads();   // protect LDS before next-iter staging overwrite
    }
}

// ---------------- 1. cast x -> bf16 ----------------
__global__ void cast_x_kernel(const float* __restrict__ x,
                              __bf16* __restrict__ xb, int n4) {
    int stride = gridDim.x * blockDim.x;
    for (int i = blockIdx.x * blockDim.x + threadIdx.x; i < n4; i += stride) {
        float4 v = ((const float4*)x)[i];
        bf16x4 o;
        o[0] = (__bf16)v.x; o[1] = (__bf16)v.y;
        o[2] = (__bf16)v.z; o[3] = (__bf16)v.w;
        ((bf16x4*)xb)[i] = o;
    }
}

// ---------------- 2. transpose-cast W (2048x6144) -> Wt (6144x2048) --------
__global__ void transpose_w_kernel(const float* __restrict__ W,
                                   __bf16* __restrict__ Wt) {
    __shared__ float tile[32][33];
    int bx = blockIdx.x * 32;  // W col / Wt row
    int by = blockIdx.y * 32;  // W row / Wt col
    int tx = threadIdx.x, ty = threadIdx.y;  // (32,8)
#pragma unroll
    for (int i = 0; i < 32; i += 8)
        tile[ty + i][tx] = W[(size_t)(by + ty + i) * N3 + bx + tx];
    __syncthreads();
#pragma unroll
    for (int i = 0; i < 32; i += 8)
        Wt[(size_t)(bx + ty + i) * C_DIM + by + tx] = (__bf16)tile[tx][ty + i];
}

// ---------------- 3. QKV GEMM ----------------
__global__ void __launch_bounds__(256)
qkv_gemm_kernel(const __bf16* __restrict__ xb, const __bf16* __restrict__ Wt,
                const float* __restrict__ bias, __bf16* __restrict__ qb,
                __bf16* __restrict__ kb, __bf16* __restrict__ vT) {
    __shared__ __bf16 As[128 * 32];
    __shared__ __bf16 Bs[128 * 32];
    f32x4 acc[4][4] = {};
    const int m0 = blockIdx.x * 128, n0 = blockIdx.y * 128;
    gemm_loop(xb, Wt, C_DIM, C_DIM, m0, n0, C_DIM / 32, As, Bs, acc);

    const int t = threadIdx.x, wv = t >> 6, lane = t & 63;
    const int wm = (wv >> 1) << 6, wn = (wv & 1) << 6;
    const int rq = (lane >> 4) << 2, cn = lane & 15;
#pragma unroll
    for (int mi = 0; mi < 4; ++mi)
#pragma unroll
        for (int ni = 0; ni < 4; ++ni) {
            int col = n0 + wn + ni * 16 + cn;
            float bv = bias[col];
#pragma unroll
            for (int r = 0; r < 4; ++r) {
                int row = m0 + wm + mi * 16 + rq + r;
                float val = acc[mi][ni][r] + bv;
                if (col < NF)
                    qb[(size_t)row * NF + col] = (__bf16)val;
                else if (col < 2 * NF)
                    kb[(size_t)row * NF + (col - NF)] = (__bf16)val;
                else
                    vT[(size_t)(col - 2 * NF) * T_DIM + row] = (__bf16)val;
            }
        }
}

// ---------------- 4. S = scale * q @ k^T (mask applied in softmax) ---------
__global__ void __launch_bounds__(256)
sc_gemm_kernel(const __bf16* __restrict__ qb, const __bf16* __restrict__ kb,
               float* __restrict__ S) {
    const int m0 = blockIdx.x * 128, n0 = blockIdx.y * 128;
    // fully above the diagonal: softmax never reads it -> write nothing
    if (n0 >= m0 + 128) return;

    __shared__ __bf16 As[128 * 32];
    __shared__ __bf16 Bs[128 * 32];
    f32x4 acc[4][4] = {};
    gemm_loop(qb, kb, NF, NF, m0, n0, NF / 32, As, Bs, acc);

    const float scale = 0.022097086912079608f;  // 1/sqrt(2048)
    const int t = threadIdx.x, wv = t >> 6, lane = t & 63;
    const int wm = (wv >> 1) << 6, wn = (wv & 1) << 6;
    const int rq = (lane >> 4) << 2, cn = lane & 15;
#pragma unroll
    for (int mi = 0; mi < 4; ++mi)
#pragma unroll
        for (int ni = 0; ni < 4; ++ni) {
            int j = n0 + wn + ni * 16 + cn;
#pragma unroll
            for (int r = 0; r < 4; ++r) {
                int i = m0 + wm + mi * 16 + rq + r;
                S[(size_t)i * T_DIM + j] = acc[mi][ni][r] * scale;
            }
        }
}

// ---------------- 5. row softmax (analytic mask), fp32 -> bf16 -------------
__global__ void __launch_bounds__(256)
softmax_kernel(const float* __restrict__ S, __bf16* __restrict__ P,
               const int* __restrict__ npadd_p) {
    const int row = blockIdx.x;
    const int t = threadIdx.x, lane = t & 63, wv = t >> 6;
    const int npadd = *npadd_p;
    __bf16* prow = P + (size_t)row * T_DIM;

    if (row < npadd) {  // padding row: p == 0
        float4 z = make_float4(0.f, 0.f, 0.f, 0.f);
        float4* p4 = (float4*)prow;  // 4096 bf16 = 512 x 16B
        for (int i = t; i < 512; i += 256) p4[i] = z;
        return;
    }

    const float* srow = S + (size_t)row * T_DIM;
    float vals[16];
#pragma unroll
    for (int k = 0; k < 16; ++k) vals[k] = NEGV;
    float mx = NEGV;
#pragma unroll
    for (int c = 0; c < 4; ++c) {
        if (c * 1024 > row) break;  // row-uniform: no divergence
        int j0 = c * 1024 + t * 4;
        float4 v = ((const float4*)srow)[c * 256 + t];
        vals[c * 4 + 0] = (j0 + 0 >= npadd && j0 + 0 <= row) ? v.x : NEGV;
        vals[c * 4 + 1] = (j0 + 1 >= npadd && j0 + 1 <= row) ? v.y : NEGV;
        vals[c * 4 + 2] = (j0 + 2 >= npadd && j0 + 2 <= row) ? v.z : NEGV;
        vals[c * 4 + 3] = (j0 + 3 >= npadd && j0 + 3 <= row) ? v.w : NEGV;
        mx = fmaxf(mx, fmaxf(fmaxf(vals[c * 4 + 0], vals[c * 4 + 1]),
                             fmaxf(vals[c * 4 + 2], vals[c * 4 + 3])));
    }
    __shared__ float wred[8];
#pragma unroll
    for (int o = 32; o > 0; o >>= 1) mx = fmaxf(mx, __shfl_xor(mx, o));
    if (lane == 0) wred[wv] = mx;
    __syncthreads();
    mx = fmaxf(fmaxf(wred[0], wred[1]), fmaxf(wred[2], wred[3]));

    float sm = 0.f;
#pragma unroll
    for (int k = 0; k < 16; ++k) {
        vals[k] = exp2f((vals[k] - mx) * 1.4426950408889634f);
        sm += vals[k];
    }
#pragma unroll
    for (int o = 32; o > 0; o >>= 1) sm += __shfl_xor(sm, o);
    if (lane == 0) wred[4 + wv] = sm;
    __syncthreads();
    sm = (wred[4] + wred[5]) + (wred[6] + wred[7]);
    float inv = 1.0f / sm;

#pragma unroll
    for (int c = 0; c < 4; ++c) {
        bf16x4 o;
        o[0] = (__bf16)(vals[c * 4 + 0] * inv);
        o[1] = (__bf16)(vals[c * 4 + 1] * inv);
        o[2] = (__bf16)(vals[c * 4 + 2] * inv);
        o[3] = (__bf16)(vals[c * 4 + 3] * inv);
        ((bf16x4*)prow)[c * 256 + t] = o;
    }
}

// ---------------- 6. y = P @ V ----------------
__global__ void __launch_bounds__(256)
pv_gemm_kernel(const __bf16* __restrict__ P, const __bf16* __restrict__ vT,
               float* __restrict__ out) {
    __shared__ __bf16 As[128 * 32];
    __shared__ __bf16 Bs[128 * 32];
    f32x4 acc[4][4] = {};
    const int m0 = blockIdx.x * 128, n0 = blockIdx.y * 128;
    const int kiters = (blockIdx.x + 1) * 4;  // causal: P[i][j]=0 for j>i
    gemm_loop(P, vT, T_DIM, T_DIM, m0, n0, kiters, As, Bs, acc);

    const int t = threadIdx.x, wv = t >> 6, lane = t & 63;
    const int wm = (wv >> 1) << 6, wn = (wv & 1) << 6;
    const int rq = (lane >> 4) << 2, cn = lane & 15;
#pragma unroll
    for (int mi = 0; mi < 4; ++mi)
#pragma unroll
        for (int ni = 0; ni < 4; ++ni) {
            int j = n0 + wn + ni * 16 + cn;
#pragma unroll
            for (int r = 0; r < 4; ++r) {
                int i = m0 + wm + mi * 16 + rq + r;
                out[(size_t)i * NF + j] = acc[mi][ni][r];
            }
        }
}

extern "C" void kernel_launch(void* const* d_in, const int* in_sizes, int n_in,
                              void* d_out, int out_size, void* d_ws,
                              size_t ws_size, hipStream_t stream) {
    const float* x = (const float*)d_in[0];
    const float* W = (const float*)d_in[1];
    const float* b = (const float*)d_in[2];
    const int* npadd = (const int*)d_in[3];
    float* out = (float*)d_out;

    char* ws = (char*)d_ws;
    // layout (152 MB total):
    __bf16* xb = (__bf16*)(ws);                          // 16 MB [0,16)
    __bf16* Wt = (__bf16*)(ws + (16ull << 20));          // 24 MB [16,40)
    __bf16* qb = (__bf16*)(ws + (40ull << 20));          // 16 MB [40,56)
    __bf16* kb = (__bf16*)(ws + (56ull << 20));          // 16 MB [56,72)
    __bf16* vT = (__bf16*)(ws + (72ull << 20));          // 16 MB [72,88)
    float*  S  = (float*)(ws + (88ull << 20));           // 64 MB [88,152)
    __bf16* P  = (__bf16*)(ws + (40ull << 20));          // 32 MB reuse qb+kb

    cast_x_kernel<<<2048, 256, 0, stream>>>(x, xb, (T_DIM * C_DIM) / 4);
    transpose_w_kernel<<<dim3(N3 / 32, C_DIM / 32), dim3(32, 8), 0, stream>>>(W, Wt);
    qkv_gemm_kernel<<<dim3(T_DIM / 128, N3 / 128), 256, 0, stream>>>(xb, Wt, b,
                                                                     qb, kb, vT);
    sc_gemm_kernel<<<dim3(T_DIM / 128, T_DIM / 128), 256, 0, stream>>>(qb, kb, S);
    softmax_kernel<<<T_DIM, 256, 0, stream>>>(S, P, npadd);
    pv_gemm_kernel<<<dim3(T_DIM / 128, NF / 128), 256, 0, stream>>>(P, vT, out);
}

// Round 3
// 411.631 us; speedup vs baseline: 1.0979x; 1.0946x over previous
//
#include <hip/hip_runtime.h>
#include <cstdint>

// ---------------------------------------------------------------------------
// PaddedSoftmaxSHCSA: y = softmax(mask(scale * (xW+b)_q @ (xW+b)_k^T)) @ (xW+b)_v
// T=4096, C=2048, NF=2048, 3*NF=6144. fp32 in/out, bf16 MFMA compute.
//
// Round 3 changes (latency/occupancy attack — R2 showed 0 bank conflicts,
// MfmaUtil 31%, Occupancy 29% = 3 waves/SIMD, reg-bound at 76 VGPR + 64 AGPR):
//  * gemm_loop fragment phase restructured: only bfr[4] + one af live
//    (was af[4]+bfr[4] = 64 VGPR of fragments) -> ~24 fewer live VGPRs.
//  * __launch_bounds__(256, 4) on all GEMM kernels: cap 128 regs/wave ->
//    4 blocks/CU (16 waves), hiding the per-iter L2 latency the 2-barrier
//    K-loop structure exposes.
//  * S stored bf16 (was fp32): halves sc-epilogue write + softmax read.
// ---------------------------------------------------------------------------

#define T_DIM 4096
#define C_DIM 2048
#define NF    2048
#define N3    6144
#define NEGV  (-1e30f)

typedef __bf16 bf16x8 __attribute__((ext_vector_type(8)));
typedef __bf16 bf16x4 __attribute__((ext_vector_type(4)));
typedef float  f32x4  __attribute__((ext_vector_type(4)));

__device__ __forceinline__ void async_cp16(const void* g, void* l) {
    __builtin_amdgcn_global_load_lds(
        reinterpret_cast<const __attribute__((address_space(1))) unsigned int*>(
            reinterpret_cast<uintptr_t>(g)),
        reinterpret_cast<__attribute__((address_space(3))) unsigned int*>(
            reinterpret_cast<uintptr_t>(l)),
        16, 0, 0);
}

// Shared 128x128-tile GEMM K-loop: C[m0..+128, n0..+128] += A @ B^T
// A: (M x K) row-major, lda elems; B: (N x K) row-major, ldb elems.
// LDS layout is XOR-swizzled: element (row, 8c+e) lives at
// row*32 + (c ^ ((row>>1)&3))*8 + e  (kills the 8-way bank conflict of the
// 64B-row-stride ds_read_b128 pattern; verified 1.26e7 -> 0 conflicts).
__device__ __forceinline__ void gemm_loop(const __bf16* A, const __bf16* B,
                                          int lda, int ldb, int m0, int n0,
                                          int kiters, __bf16* As, __bf16* Bs,
                                          f32x4 (&acc)[4][4]) {
    const int t    = threadIdx.x;          // 0..255
    const int wv   = t >> 6;               // wave 0..3
    const int lane = t & 63;
    const int srow = t >> 2;               // staging row 0..63
    // lane's LDS slot holds phys chunk (t&3) of row srow -> load the logical
    // chunk that maps there: c_log = c_phys ^ swz(row). (+64-row issue has the
    // same swz since 64 preserves (row>>1)&3.)
    const int scol = (((t & 3) ^ ((srow >> 1) & 3)) << 3);
    const int wm   = (wv >> 1) << 6;       // wave m offset 0/64
    const int wn   = (wv & 1) << 6;        // wave n offset 0/64
    const int lrow = lane & 15;
    const int kc   = lane >> 4;            // logical 16B chunk 0..3
    const int swz  = (lrow >> 1) & 3;      // row-dependent (mi*16 preserves it)
    const int rcol = ((kc ^ swz) << 3);    // physical column in LDS row

    const __bf16* ga = A + (size_t)(m0 + srow) * lda + scol;
    const __bf16* gb = B + (size_t)(n0 + srow) * ldb + scol;

    for (int kk = 0; kk < kiters; ++kk) {
        // stage A tile (128x32) and B tile (128x32); each issue = 4KB (64 rows)
        async_cp16(ga,                       &As[wv * 512]);
        async_cp16(ga + (size_t)64 * lda,    &As[wv * 512 + 2048]);
        async_cp16(gb,                       &Bs[wv * 512]);
        async_cp16(gb + (size_t)64 * ldb,    &Bs[wv * 512 + 2048]);
        ga += 32; gb += 32;
        __syncthreads();   // compiler emits vmcnt(0) drain before s_barrier

        // B fragments stay live (32 VGPR); A fragments streamed one at a time
        // (8 VGPR) -> fits the 128-reg/wave cap for 4 waves/SIMD.
        bf16x8 bfr[4];
#pragma unroll
        for (int ni = 0; ni < 4; ++ni)
            bfr[ni] = *(const bf16x8*)&Bs[(wn + ni * 16 + lrow) * 32 + rcol];
#pragma unroll
        for (int mi = 0; mi < 4; ++mi) {
            bf16x8 af = *(const bf16x8*)&As[(wm + mi * 16 + lrow) * 32 + rcol];
#pragma unroll
            for (int ni = 0; ni < 4; ++ni)
                acc[mi][ni] = __builtin_amdgcn_mfma_f32_16x16x32_bf16(
                    af, bfr[ni], acc[mi][ni], 0, 0, 0);
        }
        __syncthreads();   // protect LDS before next-iter staging overwrite
    }
}

// ---------------- 1. cast x -> bf16 ----------------
__global__ void cast_x_kernel(const float* __restrict__ x,
                              __bf16* __restrict__ xb, int n4) {
    int stride = gridDim.x * blockDim.x;
    for (int i = blockIdx.x * blockDim.x + threadIdx.x; i < n4; i += stride) {
        float4 v = ((const float4*)x)[i];
        bf16x4 o;
        o[0] = (__bf16)v.x; o[1] = (__bf16)v.y;
        o[2] = (__bf16)v.z; o[3] = (__bf16)v.w;
        ((bf16x4*)xb)[i] = o;
    }
}

// ---------------- 2. transpose-cast W (2048x6144) -> Wt (6144x2048) --------
__global__ void transpose_w_kernel(const float* __restrict__ W,
                                   __bf16* __restrict__ Wt) {
    __shared__ float tile[32][33];
    int bx = blockIdx.x * 32;  // W col / Wt row
    int by = blockIdx.y * 32;  // W row / Wt col
    int tx = threadIdx.x, ty = threadIdx.y;  // (32,8)
#pragma unroll
    for (int i = 0; i < 32; i += 8)
        tile[ty + i][tx] = W[(size_t)(by + ty + i) * N3 + bx + tx];
    __syncthreads();
#pragma unroll
    for (int i = 0; i < 32; i += 8)
        Wt[(size_t)(bx + ty + i) * C_DIM + by + tx] = (__bf16)tile[tx][ty + i];
}

// ---------------- 3. QKV GEMM ----------------
__global__ void __launch_bounds__(256, 4)
qkv_gemm_kernel(const __bf16* __restrict__ xb, const __bf16* __restrict__ Wt,
                const float* __restrict__ bias, __bf16* __restrict__ qb,
                __bf16* __restrict__ kb, __bf16* __restrict__ vT) {
    __shared__ __bf16 As[128 * 32];
    __shared__ __bf16 Bs[128 * 32];
    f32x4 acc[4][4] = {};
    const int m0 = blockIdx.x * 128, n0 = blockIdx.y * 128;
    gemm_loop(xb, Wt, C_DIM, C_DIM, m0, n0, C_DIM / 32, As, Bs, acc);

    const int t = threadIdx.x, wv = t >> 6, lane = t & 63;
    const int wm = (wv >> 1) << 6, wn = (wv & 1) << 6;
    const int rq = (lane >> 4) << 2, cn = lane & 15;
#pragma unroll
    for (int mi = 0; mi < 4; ++mi)
#pragma unroll
        for (int ni = 0; ni < 4; ++ni) {
            int col = n0 + wn + ni * 16 + cn;
            float bv = bias[col];
#pragma unroll
            for (int r = 0; r < 4; ++r) {
                int row = m0 + wm + mi * 16 + rq + r;
                float val = acc[mi][ni][r] + bv;
                if (col < NF)
                    qb[(size_t)row * NF + col] = (__bf16)val;
                else if (col < 2 * NF)
                    kb[(size_t)row * NF + (col - NF)] = (__bf16)val;
                else
                    vT[(size_t)(col - 2 * NF) * T_DIM + row] = (__bf16)val;
            }
        }
}

// ---------------- 4. S = scale * q @ k^T (bf16; mask applied in softmax) ---
__global__ void __launch_bounds__(256, 4)
sc_gemm_kernel(const __bf16* __restrict__ qb, const __bf16* __restrict__ kb,
               __bf16* __restrict__ S) {
    const int m0 = blockIdx.x * 128, n0 = blockIdx.y * 128;
    // fully above the diagonal: softmax never reads it -> write nothing
    if (n0 >= m0 + 128) return;

    __shared__ __bf16 As[128 * 32];
    __shared__ __bf16 Bs[128 * 32];
    f32x4 acc[4][4] = {};
    gemm_loop(qb, kb, NF, NF, m0, n0, NF / 32, As, Bs, acc);

    const float scale = 0.022097086912079608f;  // 1/sqrt(2048)
    const int t = threadIdx.x, wv = t >> 6, lane = t & 63;
    const int wm = (wv >> 1) << 6, wn = (wv & 1) << 6;
    const int rq = (lane >> 4) << 2, cn = lane & 15;
#pragma unroll
    for (int mi = 0; mi < 4; ++mi)
#pragma unroll
        for (int ni = 0; ni < 4; ++ni) {
            int j = n0 + wn + ni * 16 + cn;
#pragma unroll
            for (int r = 0; r < 4; ++r) {
                int i = m0 + wm + mi * 16 + rq + r;
                S[(size_t)i * T_DIM + j] = (__bf16)(acc[mi][ni][r] * scale);
            }
        }
}

// ---------------- 5. row softmax (analytic mask), bf16 in -> bf16 out ------
__global__ void __launch_bounds__(256)
softmax_kernel(const __bf16* __restrict__ S, __bf16* __restrict__ P,
               const int* __restrict__ npadd_p) {
    const int row = blockIdx.x;
    const int t = threadIdx.x, lane = t & 63, wv = t >> 6;
    const int npadd = *npadd_p;
    __bf16* prow = P + (size_t)row * T_DIM;

    if (row < npadd) {  // padding row: p == 0
        float4 z = make_float4(0.f, 0.f, 0.f, 0.f);
        float4* p4 = (float4*)prow;  // 4096 bf16 = 512 x 16B
        for (int i = t; i < 512; i += 256) p4[i] = z;
        return;
    }

    const __bf16* srow = S + (size_t)row * T_DIM;
    float vals[16];
#pragma unroll
    for (int k = 0; k < 16; ++k) vals[k] = NEGV;
    float mx = NEGV;
#pragma unroll
    for (int c = 0; c < 4; ++c) {
        if (c * 1024 > row) break;  // row-uniform: no divergence
        int j0 = c * 1024 + t * 4;
        bf16x4 v = ((const bf16x4*)srow)[c * 256 + t];
        vals[c * 4 + 0] = (j0 + 0 >= npadd && j0 + 0 <= row) ? (float)v[0] : NEGV;
        vals[c * 4 + 1] = (j0 + 1 >= npadd && j0 + 1 <= row) ? (float)v[1] : NEGV;
        vals[c * 4 + 2] = (j0 + 2 >= npadd && j0 + 2 <= row) ? (float)v[2] : NEGV;
        vals[c * 4 + 3] = (j0 + 3 >= npadd && j0 + 3 <= row) ? (float)v[3] : NEGV;
        mx = fmaxf(mx, fmaxf(fmaxf(vals[c * 4 + 0], vals[c * 4 + 1]),
                             fmaxf(vals[c * 4 + 2], vals[c * 4 + 3])));
    }
    __shared__ float wred[8];
#pragma unroll
    for (int o = 32; o > 0; o >>= 1) mx = fmaxf(mx, __shfl_xor(mx, o));
    if (lane == 0) wred[wv] = mx;
    __syncthreads();
    mx = fmaxf(fmaxf(wred[0], wred[1]), fmaxf(wred[2], wred[3]));

    float sm = 0.f;
#pragma unroll
    for (int k = 0; k < 16; ++k) {
        vals[k] = exp2f((vals[k] - mx) * 1.4426950408889634f);
        sm += vals[k];
    }
#pragma unroll
    for (int o = 32; o > 0; o >>= 1) sm += __shfl_xor(sm, o);
    if (lane == 0) wred[4 + wv] = sm;
    __syncthreads();
    sm = (wred[4] + wred[5]) + (wred[6] + wred[7]);
    float inv = 1.0f / sm;

#pragma unroll
    for (int c = 0; c < 4; ++c) {
        bf16x4 o;
        o[0] = (__bf16)(vals[c * 4 + 0] * inv);
        o[1] = (__bf16)(vals[c * 4 + 1] * inv);
        o[2] = (__bf16)(vals[c * 4 + 2] * inv);
        o[3] = (__bf16)(vals[c * 4 + 3] * inv);
        ((bf16x4*)prow)[c * 256 + t] = o;
    }
}

// ---------------- 6. y = P @ V ----------------
__global__ void __launch_bounds__(256, 4)
pv_gemm_kernel(const __bf16* __restrict__ P, const __bf16* __restrict__ vT,
               float* __restrict__ out) {
    __shared__ __bf16 As[128 * 32];
    __shared__ __bf16 Bs[128 * 32];
    f32x4 acc[4][4] = {};
    const int m0 = blockIdx.x * 128, n0 = blockIdx.y * 128;
    const int kiters = (blockIdx.x + 1) * 4;  // causal: P[i][j]=0 for j>i
    gemm_loop(P, vT, T_DIM, T_DIM, m0, n0, kiters, As, Bs, acc);

    const int t = threadIdx.x, wv = t >> 6, lane = t & 63;
    const int wm = (wv >> 1) << 6, wn = (wv & 1) << 6;
    const int rq = (lane >> 4) << 2, cn = lane & 15;
#pragma unroll
    for (int mi = 0; mi < 4; ++mi)
#pragma unroll
        for (int ni = 0; ni < 4; ++ni) {
            int j = n0 + wn + ni * 16 + cn;
#pragma unroll
            for (int r = 0; r < 4; ++r) {
                int i = m0 + wm + mi * 16 + rq + r;
                out[(size_t)i * NF + j] = acc[mi][ni][r];
            }
        }
}

extern "C" void kernel_launch(void* const* d_in, const int* in_sizes, int n_in,
                              void* d_out, int out_size, void* d_ws,
                              size_t ws_size, hipStream_t stream) {
    const float* x = (const float*)d_in[0];
    const float* W = (const float*)d_in[1];
    const float* b = (const float*)d_in[2];
    const int* npadd = (const int*)d_in[3];
    float* out = (float*)d_out;

    char* ws = (char*)d_ws;
    // layout (120 MB used):
    __bf16* xb = (__bf16*)(ws);                          // 16 MB [0,16)
    __bf16* Wt = (__bf16*)(ws + (16ull << 20));          // 24 MB [16,40)
    __bf16* qb = (__bf16*)(ws + (40ull << 20));          // 16 MB [40,56)
    __bf16* kb = (__bf16*)(ws + (56ull << 20));          // 16 MB [56,72)
    __bf16* vT = (__bf16*)(ws + (72ull << 20));          // 16 MB [72,88)
    __bf16* S  = (__bf16*)(ws + (88ull << 20));          // 32 MB [88,120)
    __bf16* P  = (__bf16*)(ws + (40ull << 20));          // 32 MB reuse qb+kb

    cast_x_kernel<<<2048, 256, 0, stream>>>(x, xb, (T_DIM * C_DIM) / 4);
    transpose_w_kernel<<<dim3(N3 / 32, C_DIM / 32), dim3(32, 8), 0, stream>>>(W, Wt);
    qkv_gemm_kernel<<<dim3(T_DIM / 128, N3 / 128), 256, 0, stream>>>(xb, Wt, b,
                                                                     qb, kb, vT);
    sc_gemm_kernel<<<dim3(T_DIM / 128, T_DIM / 128), 256, 0, stream>>>(qb, kb, S);
    softmax_kernel<<<T_DIM, 256, 0, stream>>>(S, P, npadd);
    pv_gemm_kernel<<<dim3(T_DIM / 128, NF / 128), 256, 0, stream>>>(P, vT, out);
}